// Round 15
// baseline (1150.785 us; speedup 1.0000x reference)
//
#include <hip/hip_runtime.h>

#define HH 384
#define WW 1280

typedef unsigned short u16;
typedef unsigned int u32;
typedef __attribute__((ext_vector_type(8))) short short8;
typedef __attribute__((ext_vector_type(8))) unsigned short u16x8;
typedef __attribute__((ext_vector_type(4))) float f32x4;

__device__ __forceinline__ float bf2f(u16 u){ union{u32 i;float f;}v; v.i=((u32)u)<<16; return v.f; }
__device__ __forceinline__ u16 f2bf(float f){ union{float f;u32 i;}v; v.f=f; u32 r=v.i+0x7fffu+((v.i>>16)&1u); return (u16)(r>>16); }
__device__ __forceinline__ float ftanh(float x){
  float e = __expf(2.0f*x);
  return 1.0f - 2.0f/(e+1.0f);
}
__device__ __forceinline__ void gload_lds16(const void* g, void* l){
  __builtin_amdgcn_global_load_lds((const __attribute__((address_space(1))) void*)g,
                                   (__attribute__((address_space(3))) void*)l, 16, 0, 0);
}

// Repack W1..W3 (OIHW f32) -> wq[layer][tap][kh][oc][m'] bf16 (64-B oc-rows per
// K-half), read-swizzle pre-inverted: m = m' ^ (((oc>>1)&3)<<3), ic = kh*32 + m.
__global__ __launch_bounds__(256) void prep_weights(const float* __restrict__ W1,
    const float* __restrict__ W2, const float* __restrict__ W3, u16* __restrict__ wq){
  int idx = blockIdx.x*256 + threadIdx.x;          // 3*9*2*64*32 = 110592
  if (idx >= 110592) return;
  int mp   = idx & 31;
  int oc   = (idx>>5) & 63;
  int kh   = (idx>>11) & 1;
  int tap  = (idx>>12) % 9;
  int layer= idx / 36864;
  int m    = mp ^ (((oc>>1)&3)<<3);
  int ic   = kh*32 + m;
  const float* Ws = layer==0 ? W1 : (layer==1 ? W2 : W3);
  wq[idx] = f2bf(Ws[(oc*64+ic)*9 + tap]);
}

// Layer 0: 3ch f32 NCHW -> 64ch bf16 NHWC, tanh. One pixel x 64 oc per thread.
__global__ __launch_bounds__(256) void conv0_kernel(const float* __restrict__ img,
    const float* __restrict__ W0, const float* __restrict__ b0, u16* __restrict__ out){
  int x = blockIdx.x*256 + threadIdx.x;
  int y = blockIdx.y;
  int n = blockIdx.z;
  const float* in = img + (size_t)n*3*HH*WW;
  float acc[64];
  #pragma unroll
  for (int o=0;o<64;++o) acc[o] = b0[o];
  #pragma unroll
  for (int ic=0; ic<3; ++ic)
  #pragma unroll
  for (int dy=0; dy<3; ++dy){
    int gy = y + dy - 1;
    #pragma unroll
    for (int dx=0; dx<3; ++dx){
      int gx = x + dx - 1;
      float v = 0.f;
      if (gy>=0 && gy<HH && (unsigned)gx < (unsigned)WW)
        v = in[((size_t)ic*HH + gy)*WW + gx];
      #pragma unroll
      for (int o=0;o<64;++o)
        acc[o] = fmaf(v, W0[(o*3+ic)*9 + dy*3 + dx], acc[o]);
    }
  }
  u16* op = out + ((size_t)((n*HH + y)*WW) + x)*64;
  #pragma unroll
  for (int cc=0; cc<8; ++cc){
    u16x8 v;
    #pragma unroll
    for (int k=0;k<8;++k) v[k] = f2bf(ftanh(acc[cc*8+k]));
    *(u16x8*)(op + cc*8) = v;
  }
}

// Layers 1-3: 64->64 conv as 18 half-K MFMA GEMM passes (9 taps x 2 ic-halves).
// Block: 256 px (64x*4y) x 64 oc; wave w = y-row y0+w, 4x4 16x16x32 frags.
// tileH[h]: [6 rows][66 cols][32 ch] 64-B rows; elem (r,c,m) at byte
//   (r*66+c)*64 + ((m*2) ^ (((c>>1)&3)<<4)); center staged linearly via
//   global_load_lds from pre-swizzled src, x-halo via reg+ds_write.
// Weights: wbuf[4] x 4KB (one tap-half each), staged 3 ahead, counted vmcnt.
// Both tile halves issued in prologue; half1 stays in flight until tap 3
// -> staging streams UNDER the first taps' compute (within-block overlap).
template<bool TANH>
__global__ __launch_bounds__(256) void conv64_kernel(const u16* __restrict__ in,
    const u16* __restrict__ wfL, const float* __restrict__ bias,
    const u16* __restrict__ zpad, u16* __restrict__ out){
  __shared__ __align__(16) u16 tileH[2][12672];    // 2 x 25344 B
  __shared__ __align__(16) u16 wbuf[4*2048];       // 4 x 4096 B
  const int tid = threadIdx.x;
  const int x0 = blockIdx.x*64;
  const int y0 = blockIdx.y*4;
  const int n  = blockIdx.z;
  const u16* inN = in + (size_t)n*HH*WW*64;

  const int lane = tid & 63;
  const int wv  = tid >> 6;
  const int l15 = lane & 15;
  const int lh  = lane >> 4;
  const int bswz = (lh*16) ^ (((l15>>1)&3)<<4);

#define PREFW(kk) gload_lds16( \
    wfL + (size_t)(((((kk)%9)*2 + ((kk)/9))*2048) + tid*8), \
    &wbuf[((kk)&3)*2048 + (tid & ~63)*8])

#define STAGE_TILE(h) \
  _Pragma("unroll") \
  for (int k6 = 0; k6 < 6; ++k6){ \
    int p  = k6*256 + tid; \
    int r  = p >> 8, c64 = (p >> 2) & 63, j2 = p & 3; \
    int cc_ = c64 + 1; \
    int gy = y0 - 1 + r; \
    const u16* g = ((unsigned)gy < (unsigned)HH) \
      ? inN + (((size_t)(gy*WW + x0 + c64))<<6) + (h)*32 + ((j2 ^ ((cc_>>1)&3))<<3) \
      : zpad + (j2<<3); \
    int p0 = p & ~63; \
    int r0 = p0 >> 8, c0 = (p0 >> 2) & 63; \
    gload_lds16(g, &tileH[h][(r0*66 + c0 + 1)*32]); \
  }

  // ---- prologue: halo load, w0, tile0, w1-w3, tile1 (issue order = vmcnt order)
  const u16* hsrc = zpad;
  int hdst = -1;
  {
    int i = tid;
    if (i < 96){
      int h    = i / 48;
      int i48  = i % 48;
      int r    = i48 >> 3;
      int side = (i48 >> 2) & 1;
      int jj   = i48 & 3;
      int col  = side ? 65 : 0;
      int gy   = y0 - 1 + r;
      int gx   = side ? x0 + 64 : x0 - 1;
      if ((unsigned)gy < (unsigned)HH && (unsigned)gx < (unsigned)WW)
        hsrc = inN + (((size_t)(gy*WW + gx))<<6) + h*32 + jj*8;
      hdst = h*12672 + (r*66 + col)*32 + jj*8;
    }
  }
  u16x8 haloV = *(const u16x8*)hsrc;               // 1 vmcnt op (all threads)
  __builtin_amdgcn_sched_barrier(0);
  PREFW(0);
  __builtin_amdgcn_sched_barrier(0);
  STAGE_TILE(0)
  __builtin_amdgcn_sched_barrier(0);
  PREFW(1); PREFW(2); PREFW(3);
  __builtin_amdgcn_sched_barrier(0);
  STAGE_TILE(1)
  __builtin_amdgcn_sched_barrier(0);
  // wait: halo + w0 + tile0 done; leave w1,w2,w3,tile1 (=9) in flight
  asm volatile("s_waitcnt vmcnt(9)" ::: "memory");
  if (hdst >= 0) *(u16x8*)&tileH[0][hdst] = haloV; // halo ds_write (both halves)
  asm volatile("s_waitcnt lgkmcnt(0)" ::: "memory");
  __builtin_amdgcn_s_barrier();
  __builtin_amdgcn_sched_barrier(0);

  f32x4 acc[4][4];
  #pragma unroll
  for (int mt=0;mt<4;++mt)
    #pragma unroll
    for (int nt=0;nt<4;++nt) acc[mt][nt] = (f32x4){0.f,0.f,0.f,0.f};

#define TAPK(k) { \
    const int tap_ = (k)%9, h_ = (k)/9, dy_ = tap_/3, dx_ = tap_%3; \
    if ((k) >= 1 && (k) <= 14){ PREFW((k)+3); } \
    const char* th_ = (const char*)&tileH[h_][0]; \
    const char* wb_ = (const char*)&wbuf[((k)&3)*2048]; \
    short8 a_[4], b_[4]; \
    _Pragma("unroll") \
    for (int mt=0; mt<4; ++mt){ \
      int c_ = mt*16 + l15 + dx_; \
      a_[mt] = *(const short8*)(th_ + ((wv+dy_)*66 + c_)*64 + ((lh*16) ^ (((c_>>1)&3)<<4))); \
    } \
    _Pragma("unroll") \
    for (int nt=0; nt<4; ++nt) \
      b_[nt] = *(const short8*)(wb_ + (nt*16+l15)*64 + bswz); \
    _Pragma("unroll") \
    for (int mt=0; mt<4; ++mt) \
      _Pragma("unroll") \
      for (int nt=0; nt<4; ++nt) \
        acc[mt][nt] = __builtin_amdgcn_mfma_f32_16x16x32_bf16(a_[mt], b_[nt], acc[mt][nt], 0,0,0); \
  }
#define BARR(VMLIT) \
    asm volatile("s_waitcnt vmcnt(" #VMLIT ")" ::: "memory"); \
    __builtin_amdgcn_s_barrier(); \
    __builtin_amdgcn_sched_barrier(0);

  TAPK(0)  BARR(8)
  TAPK(1)  BARR(8)
  TAPK(2)  BARR(8)
  TAPK(3)  BARR(2)
  TAPK(4)  BARR(2)
  TAPK(5)  BARR(2)
  TAPK(6)  BARR(2)
  TAPK(7)  BARR(2)
  TAPK(8)  BARR(2)
  TAPK(9)  BARR(2)
  TAPK(10) BARR(2)
  TAPK(11) BARR(2)
  TAPK(12) BARR(2)
  TAPK(13) BARR(2)
  TAPK(14) BARR(2)
  TAPK(15) BARR(1)
  TAPK(16) BARR(0)
  TAPK(17)
#undef TAPK
#undef BARR
#undef PREFW
#undef STAGE_TILE

  float bv[4];
  #pragma unroll
  for (int nt=0;nt<4;++nt) bv[nt] = bias[nt*16 + l15];
  const int gy = y0 + wv;
  u16* outR = out + (size_t)n*HH*WW*64 + (size_t)gy*WW*64;
  #pragma unroll
  for (int mt=0; mt<4; ++mt){
    #pragma unroll
    for (int r=0; r<4; ++r){
      int x = x0 + mt*16 + lh*4 + r;
      u16* op = outR + (size_t)x*64 + l15;
      #pragma unroll
      for (int nt=0; nt<4; ++nt){
        float v = acc[mt][nt][r] + bv[nt];
        if (TANH) v = ftanh(v);
        op[nt*16] = f2bf(v);
      }
    }
  }
}

// Correlation via banded MFMA GEMM, operands straight from global (no input
// LDS: no fragment reuse). Per block (b, y, 64-x tile):
//   G[x, j] = sum_c L[x,c] * R[j,c],  j window = [x0-128, x0+64)  (192 cols)
//   corr[d, x] = G[x, x-d] for d in [0,128)
// LDS: band[128][65] f32 only (33 KB, 4 blocks/CU). 1-D grid, XCD-bijective
// swizzle so x/y-adjacent blocks (2/3-overlapping R windows) share L2.
__global__ __launch_bounds__(256) void corr_kernel(const u16* __restrict__ phiL,
    const u16* __restrict__ phiR, float* __restrict__ out){
  __shared__ __align__(16) float band[128*65];     // 33280 B
  const int tid = threadIdx.x;
  int id = blockIdx.x;
  id = (id & 7)*1920 + (id >> 3);    // bijective: 15360 = 8*1920
  const int x0 = (id % 20)*64;
  const int y  = (id / 20) % 384;
  const int b  = id / 7680;
  const u16* Lrow = phiL + ((size_t)(b*HH + y)*WW)*64;
  const u16* Rrow = phiR + ((size_t)(b*HH + y)*WW)*64;

  const int lane = tid & 63;
  const int wv   = tid >> 6;        // wave owns G cols [wv*48, wv*48+48)
  const int l15  = lane & 15;
  const int lh   = lane >> 4;

  f32x4 acc[4][3];
  #pragma unroll
  for (int mt=0;mt<4;++mt)
    #pragma unroll
    for (int nt=0;nt<3;++nt) acc[mt][nt] = (f32x4){0.f,0.f,0.f,0.f};

  #pragma unroll
  for (int kh=0; kh<2; ++kh){
    const int koff = kh*32 + lh*8;  // u16 units within a pixel's 64 channels
    short8 a[4], bb[3];
    #pragma unroll
    for (int mt=0; mt<4; ++mt)
      a[mt] = *(const short8*)(Lrow + (size_t)(x0 + mt*16 + l15)*64 + koff);
    #pragma unroll
    for (int nt=0; nt<3; ++nt){
      int gx = x0 - 128 + wv*48 + nt*16 + l15;
      short8 z = (short8){0,0,0,0,0,0,0,0};
      bb[nt] = (gx >= 0) ? *(const short8*)(Rrow + (size_t)gx*64 + koff) : z;
    }
    #pragma unroll
    for (int mt=0; mt<4; ++mt)
      #pragma unroll
      for (int nt=0; nt<3; ++nt)
        acc[mt][nt] = __builtin_amdgcn_mfma_f32_16x16x32_bf16(a[mt], bb[nt], acc[mt][nt], 0,0,0);
  }

  // scatter diagonal band: x = D-row, jr = D-col, d = x - jr + 128
  #pragma unroll
  for (int mt=0; mt<4; ++mt){
    #pragma unroll
    for (int nt=0; nt<3; ++nt){
      int jr = wv*48 + nt*16 + l15;
      #pragma unroll
      for (int r=0; r<4; ++r){
        int x = mt*16 + lh*4 + r;
        int d = x - jr + 128;
        if ((unsigned)d < 128u) band[d*65 + x] = acc[mt][nt][r];
      }
    }
  }
  __syncthreads();

  // write out: 2048 float4 chunks (128 d-rows x 16), 256B contiguous per d-row
  float* ob = out + ((size_t)(b*128)*HH + (size_t)y)*WW + x0;
  #pragma unroll
  for (int it=0; it<8; ++it){
    int c = it*256 + tid;
    int d = c>>4, xq = c&15;
    const float* bp = &band[d*65 + xq*4];
    float4 v = make_float4(bp[0], bp[1], bp[2], bp[3]);
    *(float4*)&ob[(size_t)d*HH*WW + xq*4] = v;
  }
}

extern "C" void kernel_launch(void* const* d_in, const int* in_sizes, int n_in,
                              void* d_out, int out_size, void* d_ws, size_t ws_size,
                              hipStream_t stream){
  const float* l  = (const float*)d_in[0];
  const float* r  = (const float*)d_in[1];
  const float* W0 = (const float*)d_in[2];
  const float* b0 = (const float*)d_in[3];
  const float* W1 = (const float*)d_in[4];
  const float* b1 = (const float*)d_in[5];
  const float* W2 = (const float*)d_in[6];
  const float* b2 = (const float*)d_in[7];
  const float* W3 = (const float*)d_in[8];
  const float* b3 = (const float*)d_in[9];
  float* out = (float*)d_out;

  const size_t SIDE = (size_t)2*HH*WW*64;            // elements per side (NHWC bf16)
  u16* wf   = (u16*)d_ws;                            // 110592 u16
  u16* zpad = (u16*)((char*)d_ws + (1u<<20));        // 256 B zeros
  u16* BL   = (u16*)((char*)d_ws + (2u<<20));
  u16* BR   = BL + SIDE;
  u16* A    = (u16*)d_out;                           // ping scratch inside d_out

  hipMemsetAsync(zpad, 0, 256, stream);
  prep_weights<<<dim3(432), dim3(256), 0, stream>>>(W1, W2, W3, wf);

  for (int s = 0; s < 2; ++s){
    const float* img = s ? r : l;
    u16* B = s ? BR : BL;
    conv0_kernel<<<dim3(WW/256, HH, 2), dim3(256), 0, stream>>>(img, W0, b0, A);
    conv64_kernel<true ><<<dim3(WW/64, HH/4, 2), dim3(256), 0, stream>>>(A, wf + 0*36864, b1, zpad, B);
    conv64_kernel<true ><<<dim3(WW/64, HH/4, 2), dim3(256), 0, stream>>>(B, wf + 1*36864, b2, zpad, A);
    conv64_kernel<false><<<dim3(WW/64, HH/4, 2), dim3(256), 0, stream>>>(A, wf + 2*36864, b3, zpad, B);
  }

  corr_kernel<<<dim3(15360), dim3(256), 0, stream>>>(BL, BR, out);
}

// Round 16
// 1057.414 us; speedup vs baseline: 1.0883x; 1.0883x over previous
//
#include <hip/hip_runtime.h>

#define HH 384
#define WW 1280

typedef unsigned short u16;
typedef unsigned int u32;
typedef __attribute__((ext_vector_type(8))) short short8;
typedef __attribute__((ext_vector_type(8))) unsigned short u16x8;
typedef __attribute__((ext_vector_type(4))) float f32x4;

__device__ __forceinline__ float bf2f(u16 u){ union{u32 i;float f;}v; v.i=((u32)u)<<16; return v.f; }
__device__ __forceinline__ u16 f2bf(float f){ union{float f;u32 i;}v; v.f=f; u32 r=v.i+0x7fffu+((v.i>>16)&1u); return (u16)(r>>16); }
__device__ __forceinline__ float ftanh(float x){
  float e = __expf(2.0f*x);
  return 1.0f - 2.0f/(e+1.0f);
}
__device__ __forceinline__ void gload_lds16(const void* g, void* l){
  __builtin_amdgcn_global_load_lds((const __attribute__((address_space(1))) void*)g,
                                   (__attribute__((address_space(3))) void*)l, 16, 0, 0);
}

// Repack W1..W3 (OIHW f32) -> wf[layer][tap][oc][ic'] bf16, with the LDS read
// swizzle (byte ^= (oc&7)<<4) pre-inverted so linear global_load_lds staging
// lands the swizzled image: ic' = ic ^ ((oc&7)<<3).
__global__ __launch_bounds__(256) void prep_weights(const float* __restrict__ W1,
    const float* __restrict__ W2, const float* __restrict__ W3, u16* __restrict__ wf){
  int idx = blockIdx.x*256 + threadIdx.x;          // 3*9*64*64 = 110592
  if (idx >= 110592) return;
  int m    = idx & 63;
  int oc   = (idx>>6) & 63;
  int tap  = (idx>>12) % 9;
  int layer= idx / 36864;
  int ic   = m ^ ((oc&7)<<3);
  const float* Ws = layer==0 ? W1 : (layer==1 ? W2 : W3);
  wf[idx] = f2bf(Ws[(oc*64+ic)*9 + tap]);
}

// Layer 0: 3ch f32 NCHW -> 64ch bf16 NHWC, tanh. One pixel x 64 oc per thread.
// Merged L/R: n = blockIdx.z in [0,4) = side*2 + batch.
__global__ __launch_bounds__(256) void conv0_kernel(const float* __restrict__ l,
    const float* __restrict__ r, const float* __restrict__ W0,
    const float* __restrict__ b0, u16* __restrict__ out){
  int x = blockIdx.x*256 + threadIdx.x;
  int y = blockIdx.y;
  int n = blockIdx.z;
  const float* in = (n < 2 ? l : r) + (size_t)(n & 1)*3*HH*WW;
  float acc[64];
  #pragma unroll
  for (int o=0;o<64;++o) acc[o] = b0[o];
  #pragma unroll
  for (int ic=0; ic<3; ++ic)
  #pragma unroll
  for (int dy=0; dy<3; ++dy){
    int gy = y + dy - 1;
    #pragma unroll
    for (int dx=0; dx<3; ++dx){
      int gx = x + dx - 1;
      float v = 0.f;
      if (gy>=0 && gy<HH && (unsigned)gx < (unsigned)WW)
        v = in[((size_t)ic*HH + gy)*WW + gx];
      #pragma unroll
      for (int o=0;o<64;++o)
        acc[o] = fmaf(v, W0[(o*3+ic)*9 + dy*3 + dx], acc[o]);
    }
  }
  u16* op = out + ((size_t)((n*HH + y)*WW) + x)*64;
  #pragma unroll
  for (int cc=0; cc<8; ++cc){
    u16x8 v;
    #pragma unroll
    for (int k=0;k<8;++k) v[k] = f2bf(ftanh(acc[cc*8+k]));
    *(u16x8*)(op + cc*8) = v;
  }
}

// Layers 1-3: 64->64 conv as 9 shifted MFMA GEMMs. NHWC bf16 in/out.
// Merged L/R: 7680 blocks, 1-D grid with XCD-bijective swizzle (7680 = 8*960).
// Block: 256 px (64x * 4y) x 64 oc; wave w owns y-row y0+w, M=64 N=64 (4x4 frags).
// Input LDS [6 rows][66 cols][64 ic] swizzled, staged linearly from
// pre-swizzled src. Weight LDS wbuf[3], staged 2 taps ahead, counted-vmcnt
// raw barriers (no vmcnt(0) drain in the tap loop).
template<bool TANH>
__global__ __launch_bounds__(256) void conv64_kernel(const u16* __restrict__ in,
    const u16* __restrict__ wfL, const float* __restrict__ bias,
    const u16* __restrict__ zpad, u16* __restrict__ out){
  __shared__ __align__(16) u16 tile[6*66*64];      // 50688 B
  __shared__ __align__(16) u16 wbuf[3][4096];      // 3 x 8192 B
  const int tid = threadIdx.x;
  int id = blockIdx.x;
  id = (id & 7)*960 + (id >> 3);     // bijective: 7680 = 8*960
  const int x0 = (id % 20)*64;
  const int y0 = ((id / 20) % 96)*4;
  const int n  = id / 1920;          // [0,4): image index
  const u16* inN = in + (size_t)n*HH*WW*64;

  // stage input tile: 3168 16B-chunks, chunk q = (row*66+col)*8 + j
  for (int q0 = 0; q0 < 3168; q0 += 256){
    int q = q0 + tid;
    if (q < 3168){
      int row = q / 528;
      int rem = q - row*528;
      int col = rem >> 3;
      int j   = rem & 7;
      int gy = y0 - 1 + row;
      int gx = x0 - 1 + col;
      const u16* g;
      if ((unsigned)gy < (unsigned)HH && (unsigned)gx < (unsigned)WW)
        g = inN + (((size_t)(gy*WW + gx))<<6) + ((j ^ (col&7))<<3);
      else
        g = zpad + (j<<3);
      gload_lds16(g, &tile[(size_t)(q & ~63)*8]);
    }
  }
  // stage weights taps 0,1 -> wbuf[0], wbuf[1]
  #pragma unroll
  for (int t=0; t<2; ++t)
    #pragma unroll
    for (int c=0; c<2; ++c){
      int q = c*256 + tid;
      gload_lds16(wfL + (size_t)t*4096 + (size_t)q*8, &wbuf[t][(q & ~63)*8]);
    }
  // drain tile + tap0 (leave tap1's 2 chunks in flight), then barrier
  asm volatile("s_waitcnt vmcnt(2)" ::: "memory");
  __builtin_amdgcn_s_barrier();
  __builtin_amdgcn_sched_barrier(0);

  const int lane = tid & 63;
  const int wv = tid >> 6;
  const int l15 = lane & 15;
  const int lh  = lane >> 4;

  f32x4 acc[4][4];
  #pragma unroll
  for (int mt=0;mt<4;++mt)
    #pragma unroll
    for (int nt=0;nt<4;++nt) acc[mt][nt] = (f32x4){0.f,0.f,0.f,0.f};

  #pragma unroll
  for (int tap = 0; tap < 9; ++tap){
    const int dy = tap/3, dx = tap%3;
    if (tap <= 6){               // prefetch tap+2 weights (2-deep pipeline)
      const u16* wsrc = wfL + (size_t)(tap+2)*4096;
      u16* wdst = wbuf[(tap+2)%3];
      #pragma unroll
      for (int c=0;c<2;++c){
        int q = c*256 + tid;
        gload_lds16(wsrc + (size_t)q*8, &wdst[(q & ~63)*8]);
      }
    }
    const char* wb = (const char*)wbuf[tap%3];
    const char* tb = (const char*)tile;
    const int xorA = ((l15 + dx)&7)<<4;
    const int xorB = (l15&7)<<4;
    #pragma unroll
    for (int kh=0; kh<2; ++kh){
      const int kbyte = kh*64 + lh*16;
      short8 a[4], b[4];
      #pragma unroll
      for (int mt=0; mt<4; ++mt){
        int col = mt*16 + l15 + dx;
        a[mt] = *(const short8*)(tb + ((wv+dy)*66 + col)*128 + (kbyte ^ xorA));
      }
      #pragma unroll
      for (int nt=0; nt<4; ++nt){
        int oc = nt*16 + l15;
        b[nt] = *(const short8*)(wb + oc*128 + (kbyte ^ xorB));
      }
      #pragma unroll
      for (int mt=0; mt<4; ++mt)
        #pragma unroll
        for (int nt=0; nt<4; ++nt)
          acc[mt][nt] = __builtin_amdgcn_mfma_f32_16x16x32_bf16(a[mt], b[nt], acc[mt][nt], 0,0,0);
    }
    if (tap < 8){
      // drain tap+1's weight writes; keep tap+2's (just issued) in flight
      if (tap <= 6) asm volatile("s_waitcnt vmcnt(2)" ::: "memory");
      else          asm volatile("s_waitcnt vmcnt(0)" ::: "memory");
      __builtin_amdgcn_s_barrier();
      __builtin_amdgcn_sched_barrier(0);
    }
  }

  float bv[4];
  #pragma unroll
  for (int nt=0;nt<4;++nt) bv[nt] = bias[nt*16 + l15];
  const int gy = y0 + wv;
  u16* outR = out + (size_t)n*HH*WW*64 + (size_t)gy*WW*64;
  #pragma unroll
  for (int mt=0; mt<4; ++mt){
    #pragma unroll
    for (int r=0; r<4; ++r){
      int x = x0 + mt*16 + lh*4 + r;
      u16* op = outR + (size_t)x*64 + l15;
      #pragma unroll
      for (int nt=0; nt<4; ++nt){
        float v = acc[mt][nt][r] + bv[nt];
        if (TANH) v = ftanh(v);
        op[nt*16] = f2bf(v);
      }
    }
  }
}

// Correlation via banded MFMA GEMM, operands straight from global (no input
// LDS: no fragment reuse). Per block (b, y, 64-x tile):
//   G[x, j] = sum_c L[x,c] * R[j,c],  j window = [x0-128, x0+64)  (192 cols)
//   corr[d, x] = G[x, x-d] for d in [0,128)
// phi layout: [4 images][H][W][64]; images 0,1 = left, 2,3 = right.
// LDS: band[128][65] f32 only (33 KB, 4 blocks/CU). 1-D grid, XCD-bijective
// swizzle so x/y-adjacent blocks (2/3-overlapping R windows) share L2.
__global__ __launch_bounds__(256) void corr_kernel(const u16* __restrict__ phi,
    float* __restrict__ out){
  __shared__ __align__(16) float band[128*65];     // 33280 B
  const int tid = threadIdx.x;
  int id = blockIdx.x;
  id = (id & 7)*1920 + (id >> 3);    // bijective: 15360 = 8*1920
  const int x0 = (id % 20)*64;
  const int y  = (id / 20) % 384;
  const int b  = id / 7680;
  const u16* Lrow = phi + ((size_t)((b    )*HH + y)*WW)*64;
  const u16* Rrow = phi + ((size_t)((b + 2)*HH + y)*WW)*64;

  const int lane = tid & 63;
  const int wv   = tid >> 6;        // wave owns G cols [wv*48, wv*48+48)
  const int l15  = lane & 15;
  const int lh   = lane >> 4;

  f32x4 acc[4][3];
  #pragma unroll
  for (int mt=0;mt<4;++mt)
    #pragma unroll
    for (int nt=0;nt<3;++nt) acc[mt][nt] = (f32x4){0.f,0.f,0.f,0.f};

  #pragma unroll
  for (int kh=0; kh<2; ++kh){
    const int koff = kh*32 + lh*8;  // u16 units within a pixel's 64 channels
    short8 a[4], bb[3];
    #pragma unroll
    for (int mt=0; mt<4; ++mt)
      a[mt] = *(const short8*)(Lrow + (size_t)(x0 + mt*16 + l15)*64 + koff);
    #pragma unroll
    for (int nt=0; nt<3; ++nt){
      int gx = x0 - 128 + wv*48 + nt*16 + l15;
      short8 z = (short8){0,0,0,0,0,0,0,0};
      bb[nt] = (gx >= 0) ? *(const short8*)(Rrow + (size_t)gx*64 + koff) : z;
    }
    #pragma unroll
    for (int mt=0; mt<4; ++mt)
      #pragma unroll
      for (int nt=0; nt<3; ++nt)
        acc[mt][nt] = __builtin_amdgcn_mfma_f32_16x16x32_bf16(a[mt], bb[nt], acc[mt][nt], 0,0,0);
  }

  // scatter diagonal band: x = D-row, jr = D-col, d = x - jr + 128
  #pragma unroll
  for (int mt=0; mt<4; ++mt){
    #pragma unroll
    for (int nt=0; nt<3; ++nt){
      int jr = wv*48 + nt*16 + l15;
      #pragma unroll
      for (int r=0; r<4; ++r){
        int x = mt*16 + lh*4 + r;
        int d = x - jr + 128;
        if ((unsigned)d < 128u) band[d*65 + x] = acc[mt][nt][r];
      }
    }
  }
  __syncthreads();

  // write out: 2048 float4 chunks (128 d-rows x 16), 256B contiguous per d-row
  float* ob = out + ((size_t)(b*128)*HH + (size_t)y)*WW + x0;
  #pragma unroll
  for (int it=0; it<8; ++it){
    int c = it*256 + tid;
    int d = c>>4, xq = c&15;
    const float* bp = &band[d*65 + xq*4];
    float4 v = make_float4(bp[0], bp[1], bp[2], bp[3]);
    *(float4*)&ob[(size_t)d*HH*WW + xq*4] = v;
  }
}

extern "C" void kernel_launch(void* const* d_in, const int* in_sizes, int n_in,
                              void* d_out, int out_size, void* d_ws, size_t ws_size,
                              hipStream_t stream){
  const float* l  = (const float*)d_in[0];
  const float* r  = (const float*)d_in[1];
  const float* W0 = (const float*)d_in[2];
  const float* b0 = (const float*)d_in[3];
  const float* W1 = (const float*)d_in[4];
  const float* b1 = (const float*)d_in[5];
  const float* W2 = (const float*)d_in[6];
  const float* b2 = (const float*)d_in[7];
  const float* W3 = (const float*)d_in[8];
  const float* b3 = (const float*)d_in[9];
  float* out = (float*)d_out;

  u16* wf   = (u16*)d_ws;                            // 110592 u16
  u16* zpad = (u16*)((char*)d_ws + (1u<<20));        // 256 B zeros
  u16* B    = (u16*)((char*)d_ws + (2u<<20));        // pong: [4][H][W][64] bf16
  u16* A    = (u16*)d_out;                           // ping scratch inside d_out

  hipMemsetAsync(zpad, 0, 256, stream);
  prep_weights<<<dim3(432), dim3(256), 0, stream>>>(W1, W2, W3, wf);

  conv0_kernel<<<dim3(WW/256, HH, 4), dim3(256), 0, stream>>>(l, r, W0, b0, A);
  conv64_kernel<true ><<<dim3(7680), dim3(256), 0, stream>>>(A, wf + 0*36864, b1, zpad, B);
  conv64_kernel<true ><<<dim3(7680), dim3(256), 0, stream>>>(B, wf + 1*36864, b2, zpad, A);
  conv64_kernel<false><<<dim3(7680), dim3(256), 0, stream>>>(A, wf + 2*36864, b3, zpad, B);

  corr_kernel<<<dim3(15360), dim3(256), 0, stream>>>(B, out);
}

// Round 17
// 853.643 us; speedup vs baseline: 1.3481x; 1.2387x over previous
//
#include <hip/hip_runtime.h>

#define HH 384
#define WW 1280

typedef unsigned short u16;
typedef unsigned int u32;
typedef __attribute__((ext_vector_type(8))) short short8;
typedef __attribute__((ext_vector_type(8))) unsigned short u16x8;
typedef __attribute__((ext_vector_type(4))) float f32x4;

__device__ __forceinline__ float bf2f(u16 u){ union{u32 i;float f;}v; v.i=((u32)u)<<16; return v.f; }
__device__ __forceinline__ u16 f2bf(float f){ union{float f;u32 i;}v; v.f=f; u32 r=v.i+0x7fffu+((v.i>>16)&1u); return (u16)(r>>16); }
__device__ __forceinline__ float ftanh(float x){
  float e = __expf(2.0f*x);
  return 1.0f - 2.0f/(e+1.0f);
}
__device__ __forceinline__ void gload_lds16(const void* g, void* l){
  __builtin_amdgcn_global_load_lds((const __attribute__((address_space(1))) void*)g,
                                   (__attribute__((address_space(3))) void*)l, 16, 0, 0);
}

// Repack W1..W3 (OIHW f32) -> wf[layer][tap][oc][ic'] bf16 (conv64 swizzle
// pre-inverted: ic' = ic ^ ((oc&7)<<3)), and W0 -> wq0[oc][k] bf16 with
// k = ic*9 + dy*3 + dx (k<27; 27..31 zero) for the conv0 im2col MFMA.
__global__ __launch_bounds__(256) void prep_weights(const float* __restrict__ W1,
    const float* __restrict__ W2, const float* __restrict__ W3,
    const float* __restrict__ W0, u16* __restrict__ wf, u16* __restrict__ wq0){
  int idx = blockIdx.x*256 + threadIdx.x;          // 110592 + 2048
  if (idx < 110592){
    int m    = idx & 63;
    int oc   = (idx>>6) & 63;
    int tap  = (idx>>12) % 9;
    int layer= idx / 36864;
    int ic   = m ^ ((oc&7)<<3);
    const float* Ws = layer==0 ? W1 : (layer==1 ? W2 : W3);
    wf[idx] = f2bf(Ws[(oc*64+ic)*9 + tap]);
  } else if (idx < 110592 + 2048){
    int j  = idx - 110592;       // j = oc*32 + k
    int k  = j & 31;
    int oc = j >> 5;
    u16 v = 0;
    if (k < 27){
      int ic = k/9, rem = k - ic*9, dy = rem/3, dx = rem - dy*3;
      v = f2bf(W0[(oc*3+ic)*9 + dy*3 + dx]);
    }
    wq0[j] = v;
  }
}

// Layer 0 via im2col MFMA: K = 27 (3ic x 9taps) padded to 32 -> one
// 16x16x32 MFMA per (16px x 16oc) tile. Block: 64x * 4y, 64 oc; wave wv
// owns y-row y0+wv (4 px-frags x 4 oc-frags). Lane (l15,lh): pixel
// x0+mt*16+l15, k-chunk lh*8..lh*8+7. n = blockIdx.z in [0,4) = side*2+batch.
__global__ __launch_bounds__(256) void conv0_kernel(const float* __restrict__ l,
    const float* __restrict__ r, const u16* __restrict__ wq0,
    const float* __restrict__ b0, u16* __restrict__ out){
  const int tid = threadIdx.x;
  const int x0 = blockIdx.x*64;
  const int y0 = blockIdx.y*4;
  const int n  = blockIdx.z;
  const float* img = (n < 2 ? l : r) + (size_t)(n & 1)*3*HH*WW;

  const int lane = tid & 63;
  const int wv  = tid >> 6;
  const int l15 = lane & 15;
  const int lh  = lane >> 4;
  const int y   = y0 + wv;

  // decode the 8 k-values this lane holds (k = lh*8+e), hoisted once
  const float* rowp[8];
  int dxm1[8];
  #pragma unroll
  for (int e=0; e<8; ++e){
    int k  = lh*8 + e;
    int ic = k/9, rem = k - ic*9, dy = rem/3, dx = rem - dy*3;
    int gy = y + dy - 1;
    bool ok = (k < 27) && ((unsigned)gy < (unsigned)HH);
    rowp[e] = ok ? (img + ((size_t)ic*HH + gy)*WW) : (const float*)0;
    dxm1[e] = dx - 1;
  }

  // B-fragments: oc = nt*16 + l15, k-chunk lh*8 (prepacked bf16)
  short8 b[4];
  #pragma unroll
  for (int nt=0; nt<4; ++nt)
    b[nt] = *(const short8*)(wq0 + (size_t)(nt*16 + l15)*32 + lh*8);

  // A-fragments: im2col gather + bf16 pack
  short8 a[4];
  #pragma unroll
  for (int mt=0; mt<4; ++mt){
    int xb = x0 + mt*16 + l15;
    float v[8];
    #pragma unroll
    for (int e=0; e<8; ++e){
      int gx = xb + dxm1[e];
      const float* p = rowp[e];
      bool ok = (p != 0) && ((unsigned)gx < (unsigned)WW);
      v[e] = ok ? p[gx] : 0.f;
    }
    short8 af;
    #pragma unroll
    for (int e=0; e<8; ++e) af[e] = (short)f2bf(v[e]);
    a[mt] = af;
  }

  f32x4 acc[4][4];
  #pragma unroll
  for (int mt=0;mt<4;++mt)
    #pragma unroll
    for (int nt=0;nt<4;++nt) acc[mt][nt] = (f32x4){0.f,0.f,0.f,0.f};
  #pragma unroll
  for (int mt=0; mt<4; ++mt)
    #pragma unroll
    for (int nt=0; nt<4; ++nt)
      acc[mt][nt] = __builtin_amdgcn_mfma_f32_16x16x32_bf16(a[mt], b[nt], acc[mt][nt], 0,0,0);

  float bv[4];
  #pragma unroll
  for (int nt=0;nt<4;++nt) bv[nt] = b0[nt*16 + l15];
  u16* outR = out + (size_t)n*HH*WW*64 + (size_t)y*WW*64;
  #pragma unroll
  for (int mt=0; mt<4; ++mt){
    #pragma unroll
    for (int rr=0; rr<4; ++rr){
      int x = x0 + mt*16 + lh*4 + rr;
      u16* op = outR + (size_t)x*64 + l15;
      #pragma unroll
      for (int nt=0; nt<4; ++nt){
        float v = acc[mt][nt][rr] + bv[nt];
        v = ftanh(v);
        op[nt*16] = f2bf(v);
      }
    }
  }
}

// Layers 1-3: 64->64 conv as 9 shifted MFMA GEMMs. NHWC bf16 in/out.
// Merged L/R: 7680 blocks, 1-D grid with XCD-bijective swizzle (7680 = 8*960).
// Block: 256 px (64x * 4y) x 64 oc; wave w owns y-row y0+w, M=64 N=64 (4x4 frags).
// Input LDS [6 rows][66 cols][64 ic] swizzled, staged linearly from
// pre-swizzled src. Weight LDS wbuf[3], staged 2 taps ahead, counted-vmcnt
// raw barriers (no vmcnt(0) drain in the tap loop).
template<bool TANH>
__global__ __launch_bounds__(256) void conv64_kernel(const u16* __restrict__ in,
    const u16* __restrict__ wfL, const float* __restrict__ bias,
    const u16* __restrict__ zpad, u16* __restrict__ out){
  __shared__ __align__(16) u16 tile[6*66*64];      // 50688 B
  __shared__ __align__(16) u16 wbuf[3][4096];      // 3 x 8192 B
  const int tid = threadIdx.x;
  int id = blockIdx.x;
  id = (id & 7)*960 + (id >> 3);     // bijective: 7680 = 8*960
  const int x0 = (id % 20)*64;
  const int y0 = ((id / 20) % 96)*4;
  const int n  = id / 1920;          // [0,4): image index
  const u16* inN = in + (size_t)n*HH*WW*64;

  // stage input tile: 3168 16B-chunks, chunk q = (row*66+col)*8 + j
  for (int q0 = 0; q0 < 3168; q0 += 256){
    int q = q0 + tid;
    if (q < 3168){
      int row = q / 528;
      int rem = q - row*528;
      int col = rem >> 3;
      int j   = rem & 7;
      int gy = y0 - 1 + row;
      int gx = x0 - 1 + col;
      const u16* g;
      if ((unsigned)gy < (unsigned)HH && (unsigned)gx < (unsigned)WW)
        g = inN + (((size_t)(gy*WW + gx))<<6) + ((j ^ (col&7))<<3);
      else
        g = zpad + (j<<3);
      gload_lds16(g, &tile[(size_t)(q & ~63)*8]);
    }
  }
  // stage weights taps 0,1 -> wbuf[0], wbuf[1]
  #pragma unroll
  for (int t=0; t<2; ++t)
    #pragma unroll
    for (int c=0; c<2; ++c){
      int q = c*256 + tid;
      gload_lds16(wfL + (size_t)t*4096 + (size_t)q*8, &wbuf[t][(q & ~63)*8]);
    }
  // drain tile + tap0 (leave tap1's 2 chunks in flight), then barrier
  asm volatile("s_waitcnt vmcnt(2)" ::: "memory");
  __builtin_amdgcn_s_barrier();
  __builtin_amdgcn_sched_barrier(0);

  const int lane = tid & 63;
  const int wv = tid >> 6;
  const int l15 = lane & 15;
  const int lh  = lane >> 4;

  f32x4 acc[4][4];
  #pragma unroll
  for (int mt=0;mt<4;++mt)
    #pragma unroll
    for (int nt=0;nt<4;++nt) acc[mt][nt] = (f32x4){0.f,0.f,0.f,0.f};

  #pragma unroll
  for (int tap = 0; tap < 9; ++tap){
    const int dy = tap/3, dx = tap%3;
    if (tap <= 6){               // prefetch tap+2 weights (2-deep pipeline)
      const u16* wsrc = wfL + (size_t)(tap+2)*4096;
      u16* wdst = wbuf[(tap+2)%3];
      #pragma unroll
      for (int c=0;c<2;++c){
        int q = c*256 + tid;
        gload_lds16(wsrc + (size_t)q*8, &wdst[(q & ~63)*8]);
      }
    }
    const char* wb = (const char*)wbuf[tap%3];
    const char* tb = (const char*)tile;
    const int xorA = ((l15 + dx)&7)<<4;
    const int xorB = (l15&7)<<4;
    #pragma unroll
    for (int kh=0; kh<2; ++kh){
      const int kbyte = kh*64 + lh*16;
      short8 a[4], b[4];
      #pragma unroll
      for (int mt=0; mt<4; ++mt){
        int col = mt*16 + l15 + dx;
        a[mt] = *(const short8*)(tb + ((wv+dy)*66 + col)*128 + (kbyte ^ xorA));
      }
      #pragma unroll
      for (int nt=0; nt<4; ++nt){
        int oc = nt*16 + l15;
        b[nt] = *(const short8*)(wb + oc*128 + (kbyte ^ xorB));
      }
      #pragma unroll
      for (int mt=0; mt<4; ++mt)
        #pragma unroll
        for (int nt=0; nt<4; ++nt)
          acc[mt][nt] = __builtin_amdgcn_mfma_f32_16x16x32_bf16(a[mt], b[nt], acc[mt][nt], 0,0,0);
    }
    if (tap < 8){
      // drain tap+1's weight writes; keep tap+2's (just issued) in flight
      if (tap <= 6) asm volatile("s_waitcnt vmcnt(2)" ::: "memory");
      else          asm volatile("s_waitcnt vmcnt(0)" ::: "memory");
      __builtin_amdgcn_s_barrier();
      __builtin_amdgcn_sched_barrier(0);
    }
  }

  float bv[4];
  #pragma unroll
  for (int nt=0;nt<4;++nt) bv[nt] = bias[nt*16 + l15];
  const int gy = y0 + wv;
  u16* outR = out + (size_t)n*HH*WW*64 + (size_t)gy*WW*64;
  #pragma unroll
  for (int mt=0; mt<4; ++mt){
    #pragma unroll
    for (int r=0; r<4; ++r){
      int x = x0 + mt*16 + lh*4 + r;
      u16* op = outR + (size_t)x*64 + l15;
      #pragma unroll
      for (int nt=0; nt<4; ++nt){
        float v = acc[mt][nt][r] + bv[nt];
        if (TANH) v = ftanh(v);
        op[nt*16] = f2bf(v);
      }
    }
  }
}

// Correlation via banded MFMA GEMM, operands straight from global (no input
// LDS: no fragment reuse). Per block (b, y, 64-x tile):
//   G[x, j] = sum_c L[x,c] * R[j,c],  j window = [x0-128, x0+64)  (192 cols)
//   corr[d, x] = G[x, x-d] for d in [0,128)
// phi layout: [4 images][H][W][64]; images 0,1 = left, 2,3 = right.
// LDS: band[128][65] f32 only (33 KB, 4 blocks/CU). 1-D grid, XCD-bijective
// swizzle so x/y-adjacent blocks (2/3-overlapping R windows) share L2.
__global__ __launch_bounds__(256) void corr_kernel(const u16* __restrict__ phi,
    float* __restrict__ out){
  __shared__ __align__(16) float band[128*65];     // 33280 B
  const int tid = threadIdx.x;
  int id = blockIdx.x;
  id = (id & 7)*1920 + (id >> 3);    // bijective: 15360 = 8*1920
  const int x0 = (id % 20)*64;
  const int y  = (id / 20) % 384;
  const int b  = id / 7680;
  const u16* Lrow = phi + ((size_t)((b    )*HH + y)*WW)*64;
  const u16* Rrow = phi + ((size_t)((b + 2)*HH + y)*WW)*64;

  const int lane = tid & 63;
  const int wv   = tid >> 6;        // wave owns G cols [wv*48, wv*48+48)
  const int l15  = lane & 15;
  const int lh   = lane >> 4;

  f32x4 acc[4][3];
  #pragma unroll
  for (int mt=0;mt<4;++mt)
    #pragma unroll
    for (int nt=0;nt<3;++nt) acc[mt][nt] = (f32x4){0.f,0.f,0.f,0.f};

  #pragma unroll
  for (int kh=0; kh<2; ++kh){
    const int koff = kh*32 + lh*8;  // u16 units within a pixel's 64 channels
    short8 a[4], bb[3];
    #pragma unroll
    for (int mt=0; mt<4; ++mt)
      a[mt] = *(const short8*)(Lrow + (size_t)(x0 + mt*16 + l15)*64 + koff);
    #pragma unroll
    for (int nt=0; nt<3; ++nt){
      int gx = x0 - 128 + wv*48 + nt*16 + l15;
      short8 z = (short8){0,0,0,0,0,0,0,0};
      bb[nt] = (gx >= 0) ? *(const short8*)(Rrow + (size_t)gx*64 + koff) : z;
    }
    #pragma unroll
    for (int mt=0; mt<4; ++mt)
      #pragma unroll
      for (int nt=0; nt<3; ++nt)
        acc[mt][nt] = __builtin_amdgcn_mfma_f32_16x16x32_bf16(a[mt], bb[nt], acc[mt][nt], 0,0,0);
  }

  // scatter diagonal band: x = D-row, jr = D-col, d = x - jr + 128
  #pragma unroll
  for (int mt=0; mt<4; ++mt){
    #pragma unroll
    for (int nt=0; nt<3; ++nt){
      int jr = wv*48 + nt*16 + l15;
      #pragma unroll
      for (int r=0; r<4; ++r){
        int x = mt*16 + lh*4 + r;
        int d = x - jr + 128;
        if ((unsigned)d < 128u) band[d*65 + x] = acc[mt][nt][r];
      }
    }
  }
  __syncthreads();

  // write out: 2048 float4 chunks (128 d-rows x 16), 256B contiguous per d-row
  float* ob = out + ((size_t)(b*128)*HH + (size_t)y)*WW + x0;
  #pragma unroll
  for (int it=0; it<8; ++it){
    int c = it*256 + tid;
    int d = c>>4, xq = c&15;
    const float* bp = &band[d*65 + xq*4];
    float4 v = make_float4(bp[0], bp[1], bp[2], bp[3]);
    *(float4*)&ob[(size_t)d*HH*WW + xq*4] = v;
  }
}

extern "C" void kernel_launch(void* const* d_in, const int* in_sizes, int n_in,
                              void* d_out, int out_size, void* d_ws, size_t ws_size,
                              hipStream_t stream){
  const float* l  = (const float*)d_in[0];
  const float* r  = (const float*)d_in[1];
  const float* W0 = (const float*)d_in[2];
  const float* b0 = (const float*)d_in[3];
  const float* W1 = (const float*)d_in[4];
  const float* b1 = (const float*)d_in[5];
  const float* W2 = (const float*)d_in[6];
  const float* b2 = (const float*)d_in[7];
  const float* W3 = (const float*)d_in[8];
  const float* b3 = (const float*)d_in[9];
  float* out = (float*)d_out;

  u16* wf   = (u16*)d_ws;                            // 110592 u16
  u16* wq0  = (u16*)((char*)d_ws + (512u<<10));      // 2048 u16 (conv0 B)
  u16* zpad = (u16*)((char*)d_ws + (1u<<20));        // 256 B zeros
  u16* B    = (u16*)((char*)d_ws + (2u<<20));        // pong: [4][H][W][64] bf16
  u16* A    = (u16*)d_out;                           // ping scratch inside d_out

  hipMemsetAsync(zpad, 0, 256, stream);
  prep_weights<<<dim3(440), dim3(256), 0, stream>>>(W1, W2, W3, W0, wf, wq0);

  conv0_kernel<<<dim3(20, 96, 4), dim3(256), 0, stream>>>(l, r, wq0, b0, A);
  conv64_kernel<true ><<<dim3(7680), dim3(256), 0, stream>>>(A, wf + 0*36864, b1, zpad, B);
  conv64_kernel<true ><<<dim3(7680), dim3(256), 0, stream>>>(B, wf + 1*36864, b2, zpad, A);
  conv64_kernel<false><<<dim3(7680), dim3(256), 0, stream>>>(A, wf + 2*36864, b3, zpad, B);

  corr_kernel<<<dim3(15360), dim3(256), 0, stream>>>(B, out);
}